// Round 1
// baseline (2056.967 us; speedup 1.0000x reference)
//
#include <hip/hip_runtime.h>
#include <math.h>

#define B_   16
#define L_   512
#define C_   321
#define DM   512
#define DI   1024
#define DS   16
#define DTR  32
#define HOR  96
#define NROW (B_ * C_)   // 5136

// ---------------------------------------------------------------------------
// prep: h[b,c,l] = x[b,l,c] - x[b,L-1,c]   (transpose via LDS tile)
// ---------------------------------------------------------------------------
__global__ __launch_bounds__(256)
void prep_kernel(const float* __restrict__ x, float* __restrict__ h) {
    __shared__ float t[32][33];
    __shared__ float sl[32];
    int b  = blockIdx.z;
    int c0 = blockIdx.y * 32;
    int l0 = blockIdx.x * 32;
    int tx = threadIdx.x, ty = threadIdx.y;   // 32 x 8
    const float* xb = x + (size_t)b * L_ * C_;
    int c = c0 + tx;
    if (ty == 0) sl[tx] = (c < C_) ? xb[(size_t)(L_ - 1) * C_ + c] : 0.f;
#pragma unroll
    for (int i = 0; i < 4; i++) {
        int l = l0 + ty + i * 8;
        t[ty + i * 8][tx] = (c < C_) ? xb[(size_t)l * C_ + c] : 0.f;
    }
    __syncthreads();
#pragma unroll
    for (int i = 0; i < 4; i++) {
        int cc = c0 + ty + i * 8;
        if (cc < C_)
            h[((size_t)b * C_ + cc) * DM + l0 + tx] = t[tx][ty + i * 8] - sl[ty + i * 8];
    }
}

// ---------------------------------------------------------------------------
// Generic tiled fp32 GEMM:  O = A[M,K] @ W[N,K]^T + bias, fused epilogues
// EPI: 0 plain | 1 split x_/z | 2 softplus | 3 gelu | 4 final transpose+seqlast
// BM=BN=64, BK=16, 256 threads, 4x4 per thread
// ---------------------------------------------------------------------------
template <int EPI>
__global__ __launch_bounds__(256)
void gemm_k(const float* __restrict__ A, int lda,
            const float* __restrict__ W,
            const float* __restrict__ bias,
            float* __restrict__ O, float* __restrict__ O2,
            const float* __restrict__ xin,
            int M, int N, int K) {
    __shared__ float As[16][68];
    __shared__ float Bs[16][68];
    int tid = threadIdx.x;
    int tx = tid & 15, ty = tid >> 4;
    int m0 = blockIdx.y * 64, n0 = blockIdx.x * 64;
    int lk = tid & 15, lr = tid >> 4;
    float acc[4][4] = {};

    for (int k0 = 0; k0 < K; k0 += 16) {
#pragma unroll
        for (int i = 0; i < 4; i++) {
            int m = m0 + lr + i * 16;
            As[lk][lr + i * 16] = (m < M) ? A[(size_t)m * lda + k0 + lk] : 0.f;
            int n = n0 + lr + i * 16;
            Bs[lk][lr + i * 16] = (n < N) ? W[(size_t)n * K + k0 + lk] : 0.f;
        }
        __syncthreads();
#pragma unroll
        for (int k = 0; k < 16; k++) {
            float4 a4 = *(const float4*)(&As[k][ty * 4]);
            float4 b4 = *(const float4*)(&Bs[k][tx * 4]);
            float av[4] = {a4.x, a4.y, a4.z, a4.w};
            float bv[4] = {b4.x, b4.y, b4.z, b4.w};
#pragma unroll
            for (int i = 0; i < 4; i++)
#pragma unroll
                for (int j = 0; j < 4; j++) acc[i][j] += av[i] * bv[j];
        }
        __syncthreads();
    }

#pragma unroll
    for (int i = 0; i < 4; i++) {
        int m = m0 + ty * 4 + i;
        if (m >= M) continue;
#pragma unroll
        for (int j = 0; j < 4; j++) {
            int n = n0 + tx * 4 + j;
            if (n >= N) continue;
            float v = acc[i][j] + bias[n];
            if (EPI == 0) {
                O[(size_t)m * N + n] = v;
            } else if (EPI == 1) {           // split xz -> x_, z
                if (n < DI) O[(size_t)m * DI + n] = v;
                else        O2[(size_t)m * DI + (n - DI)] = v;
            } else if (EPI == 2) {           // softplus
                O[(size_t)m * N + n] = (v > 20.f) ? v : log1pf(__expf(v));
            } else if (EPI == 3) {           // exact gelu
                O[(size_t)m * N + n] = 0.5f * v * (1.f + erff(v * 0.70710678118654752f));
            } else {                         // 4: out[b,t,c] = v + seq_last[b,c]
                int b = m / C_, c = m - b * C_;
                float slv = xin[((size_t)b * L_ + (L_ - 1)) * C_ + c];
                O[((size_t)b * HOR + n) * C_ + c] = v + slv;
            }
        }
    }
}

// ---------------------------------------------------------------------------
// Fused selective scan. One thread per (b, d): 16 states in registers,
// sequential over s = 0..C_-1 (channels). Reads delta (in delta_io), x_, z,
// Bm/Cm (dbc cols 32..63); writes yz = (sum_n h_n*Cm_n + Dp*x_) * z in place
// of delta. Software prefetch of next-s operands to hide L2/HBM latency.
// ---------------------------------------------------------------------------
__global__ __launch_bounds__(256)
void scan_k(float* __restrict__ delta_io,
            const float* __restrict__ xb, const float* __restrict__ zb,
            const float* __restrict__ dbc,
            const float* __restrict__ A_log, const float* __restrict__ Dp) {
    int b = blockIdx.x >> 2;
    int d = ((blockIdx.x & 3) << 8) | threadIdx.x;   // 0..1023

    float negA[16];
    const float* al = A_log + (size_t)d * DS;
#pragma unroll
    for (int n = 0; n < DS; n++) negA[n] = -expf(al[n]);
    float dp = Dp[d];
    float st[16];
#pragma unroll
    for (int n = 0; n < DS; n++) st[n] = 0.f;

    size_t base = ((size_t)b * C_) * DI + d;
    const float* bc_base = dbc + (size_t)b * C_ * 64 + 32;

    // preload s = 0
    float de = delta_io[base], xv = xb[base], zv = zb[base];
    float4 bc[8];
#pragma unroll
    for (int q = 0; q < 8; q++) bc[q] = ((const float4*)bc_base)[q];

    for (int s = 0; s < C_ - 1; s++) {
        // prefetch s+1
        size_t nb = base + (size_t)(s + 1) * DI;
        float de_n = delta_io[nb];
        float xv_n = xb[nb];
        float zv_n = zb[nb];
        const float4* p = (const float4*)(bc_base + (size_t)(s + 1) * 64);
        float4 bcn[8];
#pragma unroll
        for (int q = 0; q < 8; q++) bcn[q] = p[q];

        // compute s
        float dx = de * xv;
        float y  = dp * xv;
        const float* bm = (const float*)bc;   // [0..15]=Bm, [16..31]=Cm
#pragma unroll
        for (int n = 0; n < DS; n++) {
            st[n] = __expf(de * negA[n]) * st[n] + dx * bm[n];
            y += st[n] * bm[16 + n];
        }
        delta_io[base + (size_t)s * DI] = y * zv;

        de = de_n; xv = xv_n; zv = zv_n;
#pragma unroll
        for (int q = 0; q < 8; q++) bc[q] = bcn[q];
    }
    // last step s = C_-1
    {
        float dx = de * xv;
        float y  = dp * xv;
        const float* bm = (const float*)bc;
#pragma unroll
        for (int n = 0; n < DS; n++) {
            st[n] = __expf(de * negA[n]) * st[n] + dx * bm[n];
            y += st[n] * bm[16 + n];
        }
        delta_io[base + (size_t)(C_ - 1) * DI] = y * zv;
    }
}

// ---------------------------------------------------------------------------
extern "C" void kernel_launch(void* const* d_in, const int* in_sizes, int n_in,
                              void* d_out, int out_size, void* d_ws, size_t ws_size,
                              hipStream_t stream) {
    const float* x     = (const float*)d_in[0];
    const float* W_in  = (const float*)d_in[1];
    const float* b_in  = (const float*)d_in[2];
    const float* W_xp  = (const float*)d_in[3];
    const float* b_xp  = (const float*)d_in[4];
    const float* W_dt  = (const float*)d_in[5];
    const float* b_dt  = (const float*)d_in[6];
    const float* A_log = (const float*)d_in[7];
    const float* Dp    = (const float*)d_in[8];
    const float* W_out = (const float*)d_in[9];
    const float* b_out = (const float*)d_in[10];
    const float* W_op  = (const float*)d_in[11];
    const float* b_op  = (const float*)d_in[12];
    float* out = (float*)d_out;

    // workspace layout (fp32): ~75 MB total
    float* h     = (float*)d_ws;                    // 5136*512
    float* xbuf  = h     + (size_t)NROW * DM;       // 5136*1024
    float* zbuf  = xbuf  + (size_t)NROW * DI;       // 5136*1024
    float* dbc   = zbuf  + (size_t)NROW * DI;       // 5136*64
    float* delta = dbc   + (size_t)NROW * 64;       // 5136*1024 (becomes yz)

    prep_kernel<<<dim3(16, 11, 16), dim3(32, 8), 0, stream>>>(x, h);

    for (int blk = 0; blk < 3; blk++) {
        // xz = h @ W_in^T + b_in  -> split x_, z
        gemm_k<1><<<dim3(32, 81), 256, 0, stream>>>(h, DM, W_in, b_in,
                                                    xbuf, zbuf, nullptr,
                                                    NROW, 2 * DI, DM);
        // dbc = x_ @ W_xp^T + b_xp
        gemm_k<0><<<dim3(1, 81), 256, 0, stream>>>(xbuf, DI, W_xp, b_xp,
                                                   dbc, nullptr, nullptr,
                                                   NROW, 64, DI);
        // delta = softplus(dbc[:, :32] @ W_dt^T + b_dt)
        gemm_k<2><<<dim3(16, 81), 256, 0, stream>>>(dbc, 64, W_dt, b_dt,
                                                    delta, nullptr, nullptr,
                                                    NROW, DI, DTR);
        // selective scan + y*z  (in place of delta)
        scan_k<<<64, 256, 0, stream>>>(delta, xbuf, zbuf, dbc, A_log, Dp);
        // h = gelu(yz @ W_out^T + b_out)
        gemm_k<3><<<dim3(8, 81), 256, 0, stream>>>(delta, DI, W_out, b_out,
                                                   h, nullptr, nullptr,
                                                   NROW, DM, DI);
    }
    // out[b,t,c] = h @ W_op^T + b_op + seq_last
    gemm_k<4><<<dim3(2, 81), 256, 0, stream>>>(h, DM, W_op, b_op,
                                               out, nullptr, x,
                                               NROW, HOR, DM);
}